// Round 1
// baseline (827.523 us; speedup 1.0000x reference)
//
#include <hip/hip_runtime.h>
#include <hip/hip_bf16.h>
#include <stdint.h>

// Problem constants (from reference): E=8, H=1024, D=2048, T=4096, K=2
#define NEXP 8
#define HDIM 1024
#define DDIM 2048
#define NTOK 4096
#define MAXROWS (NTOK * 2)

typedef __attribute__((ext_vector_type(8))) short bf16x8;
typedef __attribute__((ext_vector_type(4))) float f32x4;

// ---- ws layout (bytes) ----
#define OFF_META 0            // int nAssign
#define OFF_BASE 64           // int base[NEXP+1]
#define OFF_ATOK 256          // int assignTok[MAXROWS]
#define OFF_SLOT (OFF_ATOK + MAXROWS * 4)       // int tokSlot[NTOK][2]
#define OFF_TOKW (OFF_SLOT + NTOK * 2 * 4)      // float tokW[NTOK][2]
#define OFF_ABF  (1 << 20)                       // bf16 Abf[MAXROWS][HDIM]
#define OFF_ACT  (OFF_ABF + (size_t)MAXROWS * HDIM * 2)   // bf16 act[MAXROWS][DDIM]
#define OFF_Y    (OFF_ACT + (size_t)MAXROWS * DDIM * 2)   // bf16 Y[MAXROWS][HDIM]

__device__ __forceinline__ unsigned short f2b(float f) {
  __hip_bfloat16 h = __float2bfloat16(f);
  union { __hip_bfloat16 h; unsigned short u; } c; c.h = h; return c.u;
}
__device__ __forceinline__ float b2f(unsigned short u) {
  unsigned int x = ((unsigned int)u) << 16;
  float f; __builtin_memcpy(&f, &x, 4); return f;
}
__device__ __forceinline__ void gload_lds16(const void* g, void* l) {
  __builtin_amdgcn_global_load_lds(
      (const __attribute__((address_space(1))) unsigned int*)g,
      (__attribute__((address_space(3))) unsigned int*)l, 16, 0, 0);
}

// ---------------- routing: build per-expert compact row lists ----------------
__global__ __launch_bounds__(256) void k_route(
    const int* __restrict__ ids, const float* __restrict__ tw,
    int* __restrict__ meta, int* __restrict__ base,
    int* __restrict__ assignTok, int* __restrict__ tokSlot,
    float* __restrict__ tokW) {
  __shared__ int cnt[NEXP];
  __shared__ int cur[NEXP];
  __shared__ int sbase[NEXP + 1];
  const int tid = threadIdx.x;
  if (tid < NEXP) cnt[tid] = 0;
  __syncthreads();
  for (int t = tid; t < NTOK; t += 256) {
    const int e0 = ids[t * 2], e1 = ids[t * 2 + 1];
    if (e0 != e1) atomicAdd(&cnt[e0], 1);   // dup -> last (slot 1) wins, matches .set scatter
    atomicAdd(&cnt[e1], 1);
  }
  __syncthreads();
  if (tid == 0) {
    int s = 0;
    for (int e = 0; e < NEXP; e++) { sbase[e] = s; s += cnt[e]; }
    sbase[NEXP] = s;
    meta[0] = s;
    for (int e = 0; e <= NEXP; e++) base[e] = sbase[e];
  }
  if (tid < NEXP) cur[tid] = 0;
  __syncthreads();
  for (int t = tid; t < NTOK; t += 256) {
    const int e0 = ids[t * 2], e1 = ids[t * 2 + 1];
    int r0 = -1;
    if (e0 != e1) { r0 = sbase[e0] + atomicAdd(&cur[e0], 1); assignTok[r0] = t; }
    const int r1 = sbase[e1] + atomicAdd(&cur[e1], 1);
    assignTok[r1] = t;
    tokSlot[t * 2] = r0; tokSlot[t * 2 + 1] = r1;
    tokW[t * 2] = tw[t * 2]; tokW[t * 2 + 1] = tw[t * 2 + 1];
  }
}

// ---------------- gather tokens -> bf16 rows ----------------
__global__ __launch_bounds__(256) void k_gather(
    const float* __restrict__ hidden, const int* __restrict__ meta,
    const int* __restrict__ assignTok, unsigned short* __restrict__ Abf) {
  const int r = blockIdx.x;
  if (r >= meta[0]) return;
  const int t = assignTok[r];
  const int tid = threadIdx.x;
  const float4 v = *(const float4*)(hidden + (size_t)t * HDIM + tid * 4);
  ushort4 o;
  o.x = f2b(v.x); o.y = f2b(v.y); o.z = f2b(v.z); o.w = f2b(v.w);
  *(ushort4*)(Abf + (size_t)r * HDIM + tid * 4) = o;
}

// ---- shared helpers for the GEMM tiles ----
// LDS tiles are [128 rows][64 bf16] = rows of 128B = 8 chunks of 16B.
// XOR swizzle: logical chunk c of row r lives at chunk (c ^ (r&7)).
__device__ __forceinline__ int swz_off(int row, int chunk) {
  return row * 64 + (((chunk) ^ (row & 7)) << 3);  // in ushort units
}
// epilogue C tile [128][128] bf16, rows of 256B = 16 chunks, XOR-16 swizzle
__device__ __forceinline__ int cswz(int row, int col) {
  return row * 128 + ((((col >> 3) ^ (row & 15))) << 3) + (col & 7);
}

// Stage a [64 k][128 n] fp32 weight tile as bf16 transposed [n][k] into LDS.
// Thread t covers n = (t&31)*4 + 0..3, k = (t>>5)*8 + 0..7.
__device__ __forceinline__ void stageB(const float* __restrict__ W, int ldw,
                                       int k0, int nb, int kb,
                                       unsigned short* __restrict__ Bl) {
  bf16x8 o0, o1, o2, o3;
#pragma unroll
  for (int kk = 0; kk < 8; kk++) {
    const float4 v = *(const float4*)(W + (size_t)(k0 + kb + kk) * ldw + nb);
    o0[kk] = (short)f2b(v.x); o1[kk] = (short)f2b(v.y);
    o2[kk] = (short)f2b(v.z); o3[kk] = (short)f2b(v.w);
  }
  const int cin = kb >> 3;
  *(bf16x8*)(Bl + swz_off(nb + 0, cin)) = o0;
  *(bf16x8*)(Bl + swz_off(nb + 1, cin)) = o1;
  *(bf16x8*)(Bl + swz_off(nb + 2, cin)) = o2;
  *(bf16x8*)(Bl + swz_off(nb + 3, cin)) = o3;
}

// ---------------- phase A: fused gate+up GEMM + SwiGLU ----------------
// grid (32 m-tiles, 16 n-tiles, 8 experts), 256 threads
__global__ __launch_bounds__(256, 2) void k_gemm_up(
    const unsigned short* __restrict__ Abf, const float* __restrict__ wi0,
    const float* __restrict__ wi1, const int* __restrict__ base,
    unsigned short* __restrict__ act) {
  const int e = blockIdx.z, mt = blockIdx.x, nt = blockIdx.y;
  const int rbase = base[e], rend = base[e + 1];
  const int ne = rend - rbase;
  if (mt * 128 >= ne) return;

  __shared__ __align__(16) unsigned short lds[24576];  // 48KB: A | Bg | Bu
  unsigned short* Al = lds;
  unsigned short* Bg = lds + 8192;
  unsigned short* Bu = lds + 16384;

  const int tid = threadIdx.x;
  const int wv = tid >> 6, l = tid & 63;
  const int wm = wv >> 1, wn = wv & 1;
  const float* W0 = wi0 + (size_t)e * HDIM * DDIM + nt * 128;
  const float* W1 = wi1 + (size_t)e * HDIM * DDIM + nt * 128;
  const int nb = (tid & 31) * 4, kb = (tid >> 5) * 8;

  f32x4 accg[4][4], accu[4][4];
#pragma unroll
  for (int i = 0; i < 4; i++)
#pragma unroll
    for (int j = 0; j < 4; j++) {
      accg[i][j] = {0.f, 0.f, 0.f, 0.f};
      accu[i][j] = {0.f, 0.f, 0.f, 0.f};
    }

  for (int k0 = 0; k0 < HDIM; k0 += 64) {
    __syncthreads();
    // A: global_load_lds, source pre-swizzled so linear LDS == swizzled layout
#pragma unroll
    for (int q = 0; q < 4; q++) {
      const int rowt = (wv * 4 + q) * 8 + (l >> 3);
      const int j = l & 7;
      int r = rbase + mt * 128 + rowt;
      if (r >= rend) r = rend - 1;
      const unsigned short* gs =
          Abf + (size_t)r * HDIM + k0 + ((j ^ (rowt & 7)) << 3);
      gload_lds16(gs, Al + (wv * 4 + q) * 512);
    }
    stageB(W0, DDIM, k0, nb, kb, Bg);
    stageB(W1, DDIM, k0, nb, kb, Bu);
    __syncthreads();
#pragma unroll
    for (int kk = 0; kk < 2; kk++) {
      bf16x8 af[4], bg[4], bu[4];
#pragma unroll
      for (int mi = 0; mi < 4; mi++) {
        const int row = wm * 64 + mi * 16 + (l & 15);
        af[mi] = *(const bf16x8*)(Al + swz_off(row, kk * 4 + (l >> 4)));
      }
#pragma unroll
      for (int ni = 0; ni < 4; ni++) {
        const int row = wn * 64 + ni * 16 + (l & 15);
        const int off = swz_off(row, kk * 4 + (l >> 4));
        bg[ni] = *(const bf16x8*)(Bg + off);
        bu[ni] = *(const bf16x8*)(Bu + off);
      }
#pragma unroll
      for (int mi = 0; mi < 4; mi++)
#pragma unroll
        for (int ni = 0; ni < 4; ni++) {
          accg[mi][ni] = __builtin_amdgcn_mfma_f32_16x16x32_bf16(
              af[mi], bg[ni], accg[mi][ni], 0, 0, 0);
          accu[mi][ni] = __builtin_amdgcn_mfma_f32_16x16x32_bf16(
              af[mi], bu[ni], accu[mi][ni], 0, 0, 0);
        }
    }
  }
  // epilogue: silu(g)*u -> bf16 -> LDS (swizzled) -> coalesced global
  __syncthreads();
  unsigned short* Cl = lds;
#pragma unroll
  for (int mi = 0; mi < 4; mi++)
#pragma unroll
    for (int ni = 0; ni < 4; ni++) {
      const int col = wn * 64 + ni * 16 + (l & 15);
#pragma unroll
      for (int rr = 0; rr < 4; rr++) {
        const int row = wm * 64 + mi * 16 + (l >> 4) * 4 + rr;
        const float g = accg[mi][ni][rr];
        const float u = accu[mi][ni][rr];
        const float a = (g / (1.f + __expf(-g))) * u;
        Cl[cswz(row, col)] = f2b(a);
      }
    }
  __syncthreads();
  {
    const int row = tid >> 1, half = tid & 1;
    const int r = rbase + mt * 128 + row;
    if (r < rend) {
      unsigned short* dst = act + (size_t)r * DDIM + nt * 128 + half * 64;
#pragma unroll
      for (int q = 0; q < 8; q++) {
        const int c = half * 8 + q;
        *(bf16x8*)(dst + q * 8) =
            *(const bf16x8*)(Cl + row * 128 + ((c ^ (row & 15)) << 3));
      }
    }
  }
}

// ---------------- phase B: down-proj GEMM ----------------
// grid (32 m-tiles, 8 n-tiles, 8 experts), 256 threads
__global__ __launch_bounds__(256, 2) void k_gemm_down(
    const unsigned short* __restrict__ act, const float* __restrict__ wo,
    const int* __restrict__ base, unsigned short* __restrict__ Y) {
  const int e = blockIdx.z, mt = blockIdx.x, nt = blockIdx.y;
  const int rbase = base[e], rend = base[e + 1];
  const int ne = rend - rbase;
  if (mt * 128 >= ne) return;

  __shared__ __align__(16) unsigned short lds[16384];  // 32KB: A | Bw
  unsigned short* Al = lds;
  unsigned short* Bw = lds + 8192;

  const int tid = threadIdx.x;
  const int wv = tid >> 6, l = tid & 63;
  const int wm = wv >> 1, wn = wv & 1;
  const float* W = wo + (size_t)e * DDIM * HDIM + nt * 128;
  const int nb = (tid & 31) * 4, kb = (tid >> 5) * 8;

  f32x4 acc[4][4];
#pragma unroll
  for (int i = 0; i < 4; i++)
#pragma unroll
    for (int j = 0; j < 4; j++) acc[i][j] = {0.f, 0.f, 0.f, 0.f};

  for (int k0 = 0; k0 < DDIM; k0 += 64) {
    __syncthreads();
#pragma unroll
    for (int q = 0; q < 4; q++) {
      const int rowt = (wv * 4 + q) * 8 + (l >> 3);
      const int j = l & 7;
      int r = rbase + mt * 128 + rowt;
      if (r >= rend) r = rend - 1;
      const unsigned short* gs =
          act + (size_t)r * DDIM + k0 + ((j ^ (rowt & 7)) << 3);
      gload_lds16(gs, Al + (wv * 4 + q) * 512);
    }
    stageB(W, HDIM, k0, nb, kb, Bw);
    __syncthreads();
#pragma unroll
    for (int kk = 0; kk < 2; kk++) {
      bf16x8 af[4], bw[4];
#pragma unroll
      for (int mi = 0; mi < 4; mi++) {
        const int row = wm * 64 + mi * 16 + (l & 15);
        af[mi] = *(const bf16x8*)(Al + swz_off(row, kk * 4 + (l >> 4)));
      }
#pragma unroll
      for (int ni = 0; ni < 4; ni++) {
        const int row = wn * 64 + ni * 16 + (l & 15);
        bw[ni] = *(const bf16x8*)(Bw + swz_off(row, kk * 4 + (l >> 4)));
      }
#pragma unroll
      for (int mi = 0; mi < 4; mi++)
#pragma unroll
        for (int ni = 0; ni < 4; ni++)
          acc[mi][ni] = __builtin_amdgcn_mfma_f32_16x16x32_bf16(
              af[mi], bw[ni], acc[mi][ni], 0, 0, 0);
    }
  }
  __syncthreads();
  unsigned short* Cl = lds;  // [128][128] bf16 = 32KB
#pragma unroll
  for (int mi = 0; mi < 4; mi++)
#pragma unroll
    for (int ni = 0; ni < 4; ni++) {
      const int col = wn * 64 + ni * 16 + (l & 15);
#pragma unroll
      for (int rr = 0; rr < 4; rr++) {
        const int row = wm * 64 + mi * 16 + (l >> 4) * 4 + rr;
        Cl[cswz(row, col)] = f2b(acc[mi][ni][rr]);
      }
    }
  __syncthreads();
  {
    const int row = tid >> 1, half = tid & 1;
    const int r = rbase + mt * 128 + row;
    if (r < rend) {
      unsigned short* dst = Y + (size_t)r * HDIM + nt * 128 + half * 64;
#pragma unroll
      for (int q = 0; q < 8; q++) {
        const int c = half * 8 + q;
        *(bf16x8*)(dst + q * 8) =
            *(const bf16x8*)(Cl + row * 128 + ((c ^ (row & 15)) << 3));
      }
    }
  }
}

// ---------------- combine: out[t] = w0*Y[r0] + w1*Y[r1] ----------------
__global__ __launch_bounds__(256) void k_combine(
    const unsigned short* __restrict__ Y, const int* __restrict__ tokSlot,
    const float* __restrict__ tokW, float* __restrict__ out) {
  const int t = blockIdx.x;
  const int tid = threadIdx.x;
  int r0 = tokSlot[t * 2];
  const int r1 = tokSlot[t * 2 + 1];
  float w0 = tokW[t * 2];
  const float w1 = tokW[t * 2 + 1];
  if (r0 < 0) { w0 = 0.f; r0 = r1; }
  const ushort4 a = *(const ushort4*)(Y + (size_t)r0 * HDIM + tid * 4);
  const ushort4 b = *(const ushort4*)(Y + (size_t)r1 * HDIM + tid * 4);
  float4 o;
  o.x = w0 * b2f(a.x) + w1 * b2f(b.x);
  o.y = w0 * b2f(a.y) + w1 * b2f(b.y);
  o.z = w0 * b2f(a.z) + w1 * b2f(b.z);
  o.w = w0 * b2f(a.w) + w1 * b2f(b.w);
  *(float4*)(out + (size_t)t * HDIM + tid * 4) = o;
}

extern "C" void kernel_launch(void* const* d_in, const int* in_sizes, int n_in,
                              void* d_out, int out_size, void* d_ws,
                              size_t ws_size, hipStream_t stream) {
  const float* hidden = (const float*)d_in[0];
  const float* tw = (const float*)d_in[1];
  const int* ids = (const int*)d_in[2];
  const float* wi0 = (const float*)d_in[3];
  const float* wi1 = (const float*)d_in[4];
  const float* wo = (const float*)d_in[5];
  float* out = (float*)d_out;
  char* ws = (char*)d_ws;

  int* meta = (int*)(ws + OFF_META);
  int* base = (int*)(ws + OFF_BASE);
  int* assignTok = (int*)(ws + OFF_ATOK);
  int* tokSlot = (int*)(ws + OFF_SLOT);
  float* tokW = (float*)(ws + OFF_TOKW);
  unsigned short* Abf = (unsigned short*)(ws + OFF_ABF);
  unsigned short* act = (unsigned short*)(ws + OFF_ACT);
  unsigned short* Y = (unsigned short*)(ws + OFF_Y);

  k_route<<<dim3(1), dim3(256), 0, stream>>>(ids, tw, meta, base, assignTok,
                                             tokSlot, tokW);
  k_gather<<<dim3(MAXROWS), dim3(256), 0, stream>>>(hidden, meta, assignTok,
                                                    Abf);
  k_gemm_up<<<dim3(32, 16, NEXP), dim3(256), 0, stream>>>(Abf, wi0, wi1, base,
                                                          act);
  k_gemm_down<<<dim3(32, 8, NEXP), dim3(256), 0, stream>>>(act, wo, base, Y);
  k_combine<<<dim3(NTOK), dim3(256), 0, stream>>>(Y, tokSlot, tokW, out);
}

// Round 2
// 465.082 us; speedup vs baseline: 1.7793x; 1.7793x over previous
//
#include <hip/hip_runtime.h>
#include <hip/hip_bf16.h>
#include <stdint.h>

// Problem constants (from reference): E=8, H=1024, D=2048, T=4096, K=2
#define NEXP 8
#define HDIM 1024
#define DDIM 2048
#define NTOK 4096
#define MAXROWS (NTOK * 2)

typedef __attribute__((ext_vector_type(8))) short bf16x8;
typedef __attribute__((ext_vector_type(4))) float f32x4;

// ---- ws layout (bytes) ----
#define OFF_META 0            // int nAssign
#define OFF_BASE 64           // int base[NEXP+1]
#define OFF_ATOK 256          // int assignTok[MAXROWS]
#define OFF_SLOT (OFF_ATOK + MAXROWS * 4)       // int tokSlot[NTOK][2]
#define OFF_TOKW (OFF_SLOT + NTOK * 2 * 4)      // float tokW[NTOK][2]
#define OFF_ABF  ((size_t)1 << 20)                            // bf16 Abf[MAXROWS][HDIM]
#define OFF_ACT  (OFF_ABF + (size_t)MAXROWS * HDIM * 2)       // bf16 act[MAXROWS][DDIM]
#define OFF_Y    (OFF_ACT + (size_t)MAXROWS * DDIM * 2)       // bf16 Y[MAXROWS][HDIM]
#define OFF_W0B  (OFF_Y   + (size_t)MAXROWS * HDIM * 2)       // bf16 wi0 [E][H][D]
#define OFF_W1B  (OFF_W0B + (size_t)NEXP * HDIM * DDIM * 2)   // bf16 wi1 [E][H][D]
#define OFF_WOB  (OFF_W1B + (size_t)NEXP * HDIM * DDIM * 2)   // bf16 wo  [E][D][H]
#define WS_NEED  (OFF_WOB + (size_t)NEXP * DDIM * HDIM * 2)

__device__ __forceinline__ unsigned short f2b(float f) {
  __hip_bfloat16 h = __float2bfloat16(f);
  union { __hip_bfloat16 h; unsigned short u; } c; c.h = h; return c.u;
}
__device__ __forceinline__ float b2f(unsigned short u) {
  unsigned int x = ((unsigned int)u) << 16;
  float f; __builtin_memcpy(&f, &x, 4); return f;
}
__device__ __forceinline__ void gload_lds16(const void* g, void* l) {
  __builtin_amdgcn_global_load_lds(
      (const __attribute__((address_space(1))) unsigned int*)g,
      (__attribute__((address_space(3))) unsigned int*)l, 16, 0, 0);
}

// ---------------- weight fp32 -> bf16 conversion ----------------
__global__ __launch_bounds__(256) void k_cvtw(const float* __restrict__ src,
                                              unsigned short* __restrict__ dst,
                                              int n4) {
  int i = blockIdx.x * 256 + threadIdx.x;
  const int stride = gridDim.x * 256;
  for (; i < n4; i += stride) {
    const float4 v = ((const float4*)src)[i];
    ushort4 o;
    o.x = f2b(v.x); o.y = f2b(v.y); o.z = f2b(v.z); o.w = f2b(v.w);
    ((ushort4*)dst)[i] = o;
  }
}

// ---------------- routing: build per-expert compact row lists ----------------
__global__ __launch_bounds__(256) void k_route(
    const int* __restrict__ ids, const float* __restrict__ tw,
    int* __restrict__ meta, int* __restrict__ base,
    int* __restrict__ assignTok, int* __restrict__ tokSlot,
    float* __restrict__ tokW) {
  __shared__ int cnt[NEXP];
  __shared__ int cur[NEXP];
  __shared__ int sbase[NEXP + 1];
  const int tid = threadIdx.x;
  if (tid < NEXP) cnt[tid] = 0;
  __syncthreads();
  for (int t = tid; t < NTOK; t += 256) {
    const int e0 = ids[t * 2], e1 = ids[t * 2 + 1];
    if (e0 != e1) atomicAdd(&cnt[e0], 1);   // dup -> last (slot 1) wins, matches .set scatter
    atomicAdd(&cnt[e1], 1);
  }
  __syncthreads();
  if (tid == 0) {
    int s = 0;
    for (int e = 0; e < NEXP; e++) { sbase[e] = s; s += cnt[e]; }
    sbase[NEXP] = s;
    meta[0] = s;
    for (int e = 0; e <= NEXP; e++) base[e] = sbase[e];
  }
  if (tid < NEXP) cur[tid] = 0;
  __syncthreads();
  for (int t = tid; t < NTOK; t += 256) {
    const int e0 = ids[t * 2], e1 = ids[t * 2 + 1];
    int r0 = -1;
    if (e0 != e1) { r0 = sbase[e0] + atomicAdd(&cur[e0], 1); assignTok[r0] = t; }
    const int r1 = sbase[e1] + atomicAdd(&cur[e1], 1);
    assignTok[r1] = t;
    tokSlot[t * 2] = r0; tokSlot[t * 2 + 1] = r1;
    tokW[t * 2] = tw[t * 2]; tokW[t * 2 + 1] = tw[t * 2 + 1];
  }
}

// ---------------- gather tokens -> bf16 rows ----------------
__global__ __launch_bounds__(256) void k_gather(
    const float* __restrict__ hidden, const int* __restrict__ meta,
    const int* __restrict__ assignTok, unsigned short* __restrict__ Abf) {
  const int r = blockIdx.x;
  if (r >= meta[0]) return;
  const int t = assignTok[r];
  const int tid = threadIdx.x;
  const float4 v = *(const float4*)(hidden + (size_t)t * HDIM + tid * 4);
  ushort4 o;
  o.x = f2b(v.x); o.y = f2b(v.y); o.z = f2b(v.z); o.w = f2b(v.w);
  *(ushort4*)(Abf + (size_t)r * HDIM + tid * 4) = o;
}

// ---- shared helpers for the GEMM tiles ----
// LDS tiles are [128 rows][64 bf16] = rows of 128B = 8 chunks of 16B.
// XOR swizzle: logical chunk c of row r lives at chunk (c ^ (r&7)).
__device__ __forceinline__ int swz_off(int row, int chunk) {
  return row * 64 + (((chunk) ^ (row & 7)) << 3);  // in ushort units
}
// epilogue C tile [128][128] bf16, rows of 256B = 16 chunks, XOR-16 swizzle
__device__ __forceinline__ int cswz(int row, int col) {
  return row * 128 + ((((col >> 3) ^ (row & 15))) << 3) + (col & 7);
}

// Load a [64 k][128 n] weight tile slice into registers (transposed per-thread):
// thread covers n = nb..nb+3, k = kb..kb+7  ->  o[j] holds (n=nb+j, k=kb+0..7)
__device__ __forceinline__ void loadBtile(const unsigned short* __restrict__ W,
                                          int ldw, int k0, int nb, int kb,
                                          bf16x8 (&o)[4]) {
#pragma unroll
  for (int kk = 0; kk < 8; kk++) {
    const ushort4 v = *(const ushort4*)(W + (size_t)(k0 + kb + kk) * ldw + nb);
    o[0][kk] = (short)v.x; o[1][kk] = (short)v.y;
    o[2][kk] = (short)v.z; o[3][kk] = (short)v.w;
  }
}
__device__ __forceinline__ void loadBtile(const float* __restrict__ W,
                                          int ldw, int k0, int nb, int kb,
                                          bf16x8 (&o)[4]) {
#pragma unroll
  for (int kk = 0; kk < 8; kk++) {
    const float4 v = *(const float4*)(W + (size_t)(k0 + kb + kk) * ldw + nb);
    o[0][kk] = (short)f2b(v.x); o[1][kk] = (short)f2b(v.y);
    o[2][kk] = (short)f2b(v.z); o[3][kk] = (short)f2b(v.w);
  }
}
__device__ __forceinline__ void storeBtile(unsigned short* __restrict__ Bl,
                                           int nb, int kb, const bf16x8 (&o)[4]) {
  const int cin = kb >> 3;
  *(bf16x8*)(Bl + swz_off(nb + 0, cin)) = o[0];
  *(bf16x8*)(Bl + swz_off(nb + 1, cin)) = o[1];
  *(bf16x8*)(Bl + swz_off(nb + 2, cin)) = o[2];
  *(bf16x8*)(Bl + swz_off(nb + 3, cin)) = o[3];
}

// ---------------- phase A: fused gate+up GEMM + SwiGLU ----------------
// flat grid of 4096 blocks; bid = gg*256 + mt*8 + r, group g = gg*8+r = e*16+nt
// -> all 32 m-blocks of one (e,nt) share bid%8, i.e. land on one XCD's L2.
template <typename WT>
__global__ __launch_bounds__(256, 2) void k_gemm_up(
    const unsigned short* __restrict__ Abf, const WT* __restrict__ wi0,
    const WT* __restrict__ wi1, const int* __restrict__ base,
    unsigned short* __restrict__ act) {
  const int bid = blockIdx.x;
  const int gg = bid >> 8, mt = (bid >> 3) & 31, r8 = bid & 7;
  const int g = gg * 8 + r8;
  const int e = g >> 4, nt = g & 15;
  const int rbase = base[e], rend = base[e + 1];
  const int ne = rend - rbase;
  if (mt * 128 >= ne) return;

  __shared__ __align__(16) unsigned short lds[24576];  // 48KB: A | Bg | Bu
  unsigned short* Al = lds;
  unsigned short* Bg = lds + 8192;
  unsigned short* Bu = lds + 16384;

  const int tid = threadIdx.x;
  const int wv = tid >> 6, l = tid & 63;
  const int wm = wv >> 1, wn = wv & 1;
  const WT* W0 = wi0 + (size_t)e * HDIM * DDIM + nt * 128;
  const WT* W1 = wi1 + (size_t)e * HDIM * DDIM + nt * 128;
  const int nb = (tid & 31) * 4, kb = (tid >> 5) * 8;

  f32x4 accg[4][4], accu[4][4];
#pragma unroll
  for (int i = 0; i < 4; i++)
#pragma unroll
    for (int j = 0; j < 4; j++) {
      accg[i][j] = {0.f, 0.f, 0.f, 0.f};
      accu[i][j] = {0.f, 0.f, 0.f, 0.f};
    }

  bf16x8 pg[4], pu[4];
  loadBtile(W0, DDIM, 0, nb, kb, pg);
  loadBtile(W1, DDIM, 0, nb, kb, pu);

  for (int k0 = 0; k0 < HDIM; k0 += 64) {
    __syncthreads();  // all waves done reading LDS of previous tile
    storeBtile(Bg, nb, kb, pg);
    storeBtile(Bu, nb, kb, pu);
    // A: global_load_lds, source pre-swizzled so linear LDS == swizzled layout
#pragma unroll
    for (int q = 0; q < 4; q++) {
      const int rowt = (wv * 4 + q) * 8 + (l >> 3);
      const int j = l & 7;
      int rr = rbase + mt * 128 + rowt;
      if (rr >= rend) rr = rend - 1;
      const unsigned short* gs =
          Abf + (size_t)rr * HDIM + k0 + ((j ^ (rowt & 7)) << 3);
      gload_lds16(gs, Al + (wv * 4 + q) * 512);
    }
    __syncthreads();  // drains A vmcnt + B ds_writes; nothing else outstanding
    // T14: issue next tile's B loads now — latency hides under the MFMAs
    if (k0 + 64 < HDIM) {
      loadBtile(W0, DDIM, k0 + 64, nb, kb, pg);
      loadBtile(W1, DDIM, k0 + 64, nb, kb, pu);
    }
#pragma unroll
    for (int kk = 0; kk < 2; kk++) {
      bf16x8 af[4], bg[4], bu[4];
#pragma unroll
      for (int mi = 0; mi < 4; mi++) {
        const int row = wm * 64 + mi * 16 + (l & 15);
        af[mi] = *(const bf16x8*)(Al + swz_off(row, kk * 4 + (l >> 4)));
      }
#pragma unroll
      for (int ni = 0; ni < 4; ni++) {
        const int row = wn * 64 + ni * 16 + (l & 15);
        const int off = swz_off(row, kk * 4 + (l >> 4));
        bg[ni] = *(const bf16x8*)(Bg + off);
        bu[ni] = *(const bf16x8*)(Bu + off);
      }
#pragma unroll
      for (int mi = 0; mi < 4; mi++)
#pragma unroll
        for (int ni = 0; ni < 4; ni++) {
          accg[mi][ni] = __builtin_amdgcn_mfma_f32_16x16x32_bf16(
              af[mi], bg[ni], accg[mi][ni], 0, 0, 0);
          accu[mi][ni] = __builtin_amdgcn_mfma_f32_16x16x32_bf16(
              af[mi], bu[ni], accu[mi][ni], 0, 0, 0);
        }
    }
  }
  // epilogue: silu(g)*u -> bf16 -> LDS (swizzled) -> coalesced global
  __syncthreads();
  unsigned short* Cl = lds;
#pragma unroll
  for (int mi = 0; mi < 4; mi++)
#pragma unroll
    for (int ni = 0; ni < 4; ni++) {
      const int col = wn * 64 + ni * 16 + (l & 15);
#pragma unroll
      for (int rr = 0; rr < 4; rr++) {
        const int row = wm * 64 + mi * 16 + (l >> 4) * 4 + rr;
        const float gv = accg[mi][ni][rr];
        const float uv = accu[mi][ni][rr];
        const float a = (gv / (1.f + __expf(-gv))) * uv;
        Cl[cswz(row, col)] = f2b(a);
      }
    }
  __syncthreads();
  {
    const int row = tid >> 1, half = tid & 1;
    const int rw = rbase + mt * 128 + row;
    if (rw < rend) {
      unsigned short* dst = act + (size_t)rw * DDIM + nt * 128 + half * 64;
#pragma unroll
      for (int q = 0; q < 8; q++) {
        const int c = half * 8 + q;
        *(bf16x8*)(dst + q * 8) =
            *(const bf16x8*)(Cl + row * 128 + ((c ^ (row & 15)) << 3));
      }
    }
  }
}

// ---------------- phase B: down-proj GEMM ----------------
// flat grid of 2048 blocks; bid = gg*256 + mt*8 + r, g = gg*8+r = e*8+nt
template <typename WT>
__global__ __launch_bounds__(256, 2) void k_gemm_down(
    const unsigned short* __restrict__ act, const WT* __restrict__ wo,
    const int* __restrict__ base, unsigned short* __restrict__ Y) {
  const int bid = blockIdx.x;
  const int gg = bid >> 8, mt = (bid >> 3) & 31, r8 = bid & 7;
  const int g = gg * 8 + r8;
  const int e = g >> 3, nt = g & 7;
  const int rbase = base[e], rend = base[e + 1];
  const int ne = rend - rbase;
  if (mt * 128 >= ne) return;

  __shared__ __align__(16) unsigned short lds[16384];  // 32KB: A | Bw
  unsigned short* Al = lds;
  unsigned short* Bw = lds + 8192;

  const int tid = threadIdx.x;
  const int wv = tid >> 6, l = tid & 63;
  const int wm = wv >> 1, wn = wv & 1;
  const WT* W = wo + (size_t)e * DDIM * HDIM + nt * 128;
  const int nb = (tid & 31) * 4, kb = (tid >> 5) * 8;

  f32x4 acc[4][4];
#pragma unroll
  for (int i = 0; i < 4; i++)
#pragma unroll
    for (int j = 0; j < 4; j++) acc[i][j] = {0.f, 0.f, 0.f, 0.f};

  bf16x8 pw[4];
  loadBtile(W, HDIM, 0, nb, kb, pw);

  for (int k0 = 0; k0 < DDIM; k0 += 64) {
    __syncthreads();
    storeBtile(Bw, nb, kb, pw);
#pragma unroll
    for (int q = 0; q < 4; q++) {
      const int rowt = (wv * 4 + q) * 8 + (l >> 3);
      const int j = l & 7;
      int rr = rbase + mt * 128 + rowt;
      if (rr >= rend) rr = rend - 1;
      const unsigned short* gs =
          act + (size_t)rr * DDIM + k0 + ((j ^ (rowt & 7)) << 3);
      gload_lds16(gs, Al + (wv * 4 + q) * 512);
    }
    __syncthreads();
    if (k0 + 64 < DDIM) loadBtile(W, HDIM, k0 + 64, nb, kb, pw);
#pragma unroll
    for (int kk = 0; kk < 2; kk++) {
      bf16x8 af[4], bw[4];
#pragma unroll
      for (int mi = 0; mi < 4; mi++) {
        const int row = wm * 64 + mi * 16 + (l & 15);
        af[mi] = *(const bf16x8*)(Al + swz_off(row, kk * 4 + (l >> 4)));
      }
#pragma unroll
      for (int ni = 0; ni < 4; ni++) {
        const int row = wn * 64 + ni * 16 + (l & 15);
        bw[ni] = *(const bf16x8*)(Bw + swz_off(row, kk * 4 + (l >> 4)));
      }
#pragma unroll
      for (int mi = 0; mi < 4; mi++)
#pragma unroll
        for (int ni = 0; ni < 4; ni++)
          acc[mi][ni] = __builtin_amdgcn_mfma_f32_16x16x32_bf16(
              af[mi], bw[ni], acc[mi][ni], 0, 0, 0);
    }
  }
  __syncthreads();
  unsigned short* Cl = lds;  // [128][128] bf16 = 32KB
#pragma unroll
  for (int mi = 0; mi < 4; mi++)
#pragma unroll
    for (int ni = 0; ni < 4; ni++) {
      const int col = wn * 64 + ni * 16 + (l & 15);
#pragma unroll
      for (int rr = 0; rr < 4; rr++) {
        const int row = wm * 64 + mi * 16 + (l >> 4) * 4 + rr;
        Cl[cswz(row, col)] = f2b(acc[mi][ni][rr]);
      }
    }
  __syncthreads();
  {
    const int row = tid >> 1, half = tid & 1;
    const int rw = rbase + mt * 128 + row;
    if (rw < rend) {
      unsigned short* dst = Y + (size_t)rw * HDIM + nt * 128 + half * 64;
#pragma unroll
      for (int q = 0; q < 8; q++) {
        const int c = half * 8 + q;
        *(bf16x8*)(dst + q * 8) =
            *(const bf16x8*)(Cl + row * 128 + ((c ^ (row & 15)) << 3));
      }
    }
  }
}

// ---------------- combine: out[t] = w0*Y[r0] + w1*Y[r1] ----------------
__global__ __launch_bounds__(256) void k_combine(
    const unsigned short* __restrict__ Y, const int* __restrict__ tokSlot,
    const float* __restrict__ tokW, float* __restrict__ out) {
  const int t = blockIdx.x;
  const int tid = threadIdx.x;
  int r0 = tokSlot[t * 2];
  const int r1 = tokSlot[t * 2 + 1];
  float w0 = tokW[t * 2];
  const float w1 = tokW[t * 2 + 1];
  if (r0 < 0) { w0 = 0.f; r0 = r1; }
  const ushort4 a = *(const ushort4*)(Y + (size_t)r0 * HDIM + tid * 4);
  const ushort4 b = *(const ushort4*)(Y + (size_t)r1 * HDIM + tid * 4);
  float4 o;
  o.x = w0 * b2f(a.x) + w1 * b2f(b.x);
  o.y = w0 * b2f(a.y) + w1 * b2f(b.y);
  o.z = w0 * b2f(a.z) + w1 * b2f(b.z);
  o.w = w0 * b2f(a.w) + w1 * b2f(b.w);
  *(float4*)(out + (size_t)t * HDIM + tid * 4) = o;
}

extern "C" void kernel_launch(void* const* d_in, const int* in_sizes, int n_in,
                              void* d_out, int out_size, void* d_ws,
                              size_t ws_size, hipStream_t stream) {
  const float* hidden = (const float*)d_in[0];
  const float* tw = (const float*)d_in[1];
  const int* ids = (const int*)d_in[2];
  const float* wi0 = (const float*)d_in[3];
  const float* wi1 = (const float*)d_in[4];
  const float* wo = (const float*)d_in[5];
  float* out = (float*)d_out;
  char* ws = (char*)d_ws;

  int* meta = (int*)(ws + OFF_META);
  int* base = (int*)(ws + OFF_BASE);
  int* assignTok = (int*)(ws + OFF_ATOK);
  int* tokSlot = (int*)(ws + OFF_SLOT);
  float* tokW = (float*)(ws + OFF_TOKW);
  unsigned short* Abf = (unsigned short*)(ws + OFF_ABF);
  unsigned short* act = (unsigned short*)(ws + OFF_ACT);
  unsigned short* Y = (unsigned short*)(ws + OFF_Y);

  k_route<<<dim3(1), dim3(256), 0, stream>>>(ids, tw, meta, base, assignTok,
                                             tokSlot, tokW);
  k_gather<<<dim3(MAXROWS), dim3(256), 0, stream>>>(hidden, meta, assignTok,
                                                    Abf);
  if (ws_size >= WS_NEED) {
    unsigned short* W0b = (unsigned short*)(ws + OFF_W0B);
    unsigned short* W1b = (unsigned short*)(ws + OFF_W1B);
    unsigned short* Wob = (unsigned short*)(ws + OFF_WOB);
    const int n4 = NEXP * HDIM * DDIM / 4;
    k_cvtw<<<dim3(2048), dim3(256), 0, stream>>>(wi0, W0b, n4);
    k_cvtw<<<dim3(2048), dim3(256), 0, stream>>>(wi1, W1b, n4);
    k_cvtw<<<dim3(2048), dim3(256), 0, stream>>>(wo, Wob, n4);
    k_gemm_up<unsigned short><<<dim3(4096), dim3(256), 0, stream>>>(
        Abf, W0b, W1b, base, act);
    k_gemm_down<unsigned short><<<dim3(2048), dim3(256), 0, stream>>>(
        act, Wob, base, Y);
  } else {
    k_gemm_up<float><<<dim3(4096), dim3(256), 0, stream>>>(Abf, wi0, wi1, base,
                                                           act);
    k_gemm_down<float><<<dim3(2048), dim3(256), 0, stream>>>(act, wo, base, Y);
  }
  k_combine<<<dim3(NTOK), dim3(256), 0, stream>>>(Y, tokSlot, tokW, out);
}

// Round 6
// 430.517 us; speedup vs baseline: 1.9222x; 1.0803x over previous
//
#include <hip/hip_runtime.h>
#include <hip/hip_bf16.h>
#include <stdint.h>

// Problem constants (from reference): E=8, H=1024, D=2048, T=4096, K=2
#define NEXP 8
#define HDIM 1024
#define DDIM 2048
#define NTOK 4096
#define MAXROWS (NTOK * 2)

typedef __attribute__((ext_vector_type(8))) short bf16x8;
typedef __attribute__((ext_vector_type(4))) float f32x4;

// ---- ws layout (bytes) ----
#define OFF_META 0            // int nAssign
#define OFF_BASE 64           // int base[NEXP+1]
#define OFF_ATOK 256          // int assignTok[MAXROWS]
#define OFF_SLOT (OFF_ATOK + MAXROWS * 4)       // int tokSlot[NTOK][2]
#define OFF_TOKW (OFF_SLOT + NTOK * 2 * 4)      // float tokW[NTOK][2]
#define OFF_ABF  ((size_t)1 << 20)                            // bf16 Abf[MAXROWS][HDIM]
#define OFF_ACT  (OFF_ABF + (size_t)MAXROWS * HDIM * 2)       // bf16 act[MAXROWS][DDIM]
#define OFF_Y    (OFF_ACT + (size_t)MAXROWS * DDIM * 2)       // bf16 Y[MAXROWS][HDIM]
#define OFF_W0B  (OFF_Y   + (size_t)MAXROWS * HDIM * 2)       // bf16 wi0 [E][H][D]
#define OFF_W1B  (OFF_W0B + (size_t)NEXP * HDIM * DDIM * 2)   // bf16 wi1 [E][H][D]
#define OFF_WOB  (OFF_W1B + (size_t)NEXP * HDIM * DDIM * 2)   // bf16 wo  [E][D][H]
#define WS_NEED  (OFF_WOB + (size_t)NEXP * DDIM * HDIM * 2)

// lgkm-only barrier: orders LDS ops; leaves global/DMA loads in flight.
#define BAR_LGKM() asm volatile("s_waitcnt lgkmcnt(0)\ns_barrier" ::: "memory")
// full barrier: drains DMA (vmcnt) + LDS, then syncs. Placed AFTER the MFMA
// phase so the ~500cy load latency is already covered by compute.
#define BAR_FULL() \
  asm volatile("s_waitcnt vmcnt(0) lgkmcnt(0)\ns_barrier" ::: "memory")

__device__ __forceinline__ unsigned short f2b(float f) {
  __hip_bfloat16 h = __float2bfloat16(f);
  union { __hip_bfloat16 h; unsigned short u; } c; c.h = h; return c.u;
}
__device__ __forceinline__ float b2f(unsigned short u) {
  unsigned int x = ((unsigned int)u) << 16;
  float f; __builtin_memcpy(&f, &x, 4); return f;
}
__device__ __forceinline__ void gload_lds16(const void* g, void* l) {
  __builtin_amdgcn_global_load_lds(
      (const __attribute__((address_space(1))) unsigned int*)g,
      (__attribute__((address_space(3))) unsigned int*)l, 16, 0, 0);
}

// ---------------- weight fp32 -> bf16 conversion (3 arrays, 1 launch) ------
__global__ __launch_bounds__(256) void k_cvtw3(
    const float* __restrict__ s0, const float* __restrict__ s1,
    const float* __restrict__ s2, unsigned short* __restrict__ d0,
    unsigned short* __restrict__ d1, unsigned short* __restrict__ d2, int n4) {
  const float* src = blockIdx.y == 0 ? s0 : (blockIdx.y == 1 ? s1 : s2);
  unsigned short* dst = blockIdx.y == 0 ? d0 : (blockIdx.y == 1 ? d1 : d2);
  int i = blockIdx.x * 256 + threadIdx.x;
  const int stride = gridDim.x * 256;
  for (; i < n4; i += stride) {
    const float4 v = ((const float4*)src)[i];
    ushort4 o;
    o.x = f2b(v.x); o.y = f2b(v.y); o.z = f2b(v.z); o.w = f2b(v.w);
    ((ushort4*)dst)[i] = o;
  }
}

// ---------------- routing: build per-expert compact row lists ----------------
__global__ __launch_bounds__(256) void k_route(
    const int* __restrict__ ids, const float* __restrict__ tw,
    int* __restrict__ meta, int* __restrict__ base,
    int* __restrict__ assignTok, int* __restrict__ tokSlot,
    float* __restrict__ tokW) {
  __shared__ int cnt[NEXP];
  __shared__ int cur[NEXP];
  __shared__ int sbase[NEXP + 1];
  const int tid = threadIdx.x;
  if (tid < NEXP) cnt[tid] = 0;
  __syncthreads();
  for (int t = tid; t < NTOK; t += 256) {
    const int e0 = ids[t * 2], e1 = ids[t * 2 + 1];
    if (e0 != e1) atomicAdd(&cnt[e0], 1);   // dup -> last (slot 1) wins, matches .set scatter
    atomicAdd(&cnt[e1], 1);
  }
  __syncthreads();
  if (tid == 0) {
    int s = 0;
    for (int e = 0; e < NEXP; e++) { sbase[e] = s; s += cnt[e]; }
    sbase[NEXP] = s;
    meta[0] = s;
    for (int e = 0; e <= NEXP; e++) base[e] = sbase[e];
  }
  if (tid < NEXP) cur[tid] = 0;
  __syncthreads();
  for (int t = tid; t < NTOK; t += 256) {
    const int e0 = ids[t * 2], e1 = ids[t * 2 + 1];
    int r0 = -1;
    if (e0 != e1) { r0 = sbase[e0] + atomicAdd(&cur[e0], 1); assignTok[r0] = t; }
    const int r1 = sbase[e1] + atomicAdd(&cur[e1], 1);
    assignTok[r1] = t;
    tokSlot[t * 2] = r0; tokSlot[t * 2 + 1] = r1;
    tokW[t * 2] = tw[t * 2]; tokW[t * 2 + 1] = tw[t * 2 + 1];
  }
}

// ---------------- gather tokens -> bf16 rows ----------------
__global__ __launch_bounds__(256) void k_gather(
    const float* __restrict__ hidden, const int* __restrict__ meta,
    const int* __restrict__ assignTok, unsigned short* __restrict__ Abf) {
  const int r = blockIdx.x;
  if (r >= meta[0]) return;
  const int t = assignTok[r];
  const int tid = threadIdx.x;
  const float4 v = *(const float4*)(hidden + (size_t)t * HDIM + tid * 4);
  ushort4 o;
  o.x = f2b(v.x); o.y = f2b(v.y); o.z = f2b(v.z); o.w = f2b(v.w);
  *(ushort4*)(Abf + (size_t)r * HDIM + tid * 4) = o;
}

// ---- shared helpers for the GEMM tiles ----
// LDS tiles are [128 rows][64 bf16] = rows of 128B = 8 chunks of 16B.
// Swizzle q(row) = (row ^ (row>>2)) & 7: structural-floor conflicts for BOTH
//  - reads (16 consecutive rows per lane-group): q covers 0..7 twice
//  - writes (rows 4a, a=0..31): q covers all 8 values evenly
__device__ __forceinline__ int swz_q(int row) { return (row ^ (row >> 2)) & 7; }
__device__ __forceinline__ int swz_off(int row, int chunk) {
  return row * 64 + ((chunk ^ swz_q(row)) << 3);  // in ushort units
}
// epilogue C tile [128][128] bf16, rows of 256B = 16 chunks, XOR-16 swizzle
__device__ __forceinline__ int cswz(int row, int col) {
  return row * 128 + ((((col >> 3) ^ (row & 15))) << 3) + (col & 7);
}

// Load a [64 k][128 n] weight tile slice into registers (transposed per-thread):
// thread covers n = nb..nb+3, k = kb..kb+7  ->  o[j] holds (n=nb+j, k=kb+0..7)
__device__ __forceinline__ void loadBtile(const unsigned short* __restrict__ W,
                                          int ldw, int k0, int nb, int kb,
                                          bf16x8 (&o)[4]) {
#pragma unroll
  for (int kk = 0; kk < 8; kk++) {
    const ushort4 v = *(const ushort4*)(W + (size_t)(k0 + kb + kk) * ldw + nb);
    o[0][kk] = (short)v.x; o[1][kk] = (short)v.y;
    o[2][kk] = (short)v.z; o[3][kk] = (short)v.w;
  }
}
__device__ __forceinline__ void loadBtile(const float* __restrict__ W,
                                          int ldw, int k0, int nb, int kb,
                                          bf16x8 (&o)[4]) {
#pragma unroll
  for (int kk = 0; kk < 8; kk++) {
    const float4 v = *(const float4*)(W + (size_t)(k0 + kb + kk) * ldw + nb);
    o[0][kk] = (short)f2b(v.x); o[1][kk] = (short)f2b(v.y);
    o[2][kk] = (short)f2b(v.z); o[3][kk] = (short)f2b(v.w);
  }
}
__device__ __forceinline__ void storeBtile(unsigned short* Bl, int nb, int kb,
                                           const bf16x8 (&o)[4]) {
  const int cin = kb >> 3;
  *(bf16x8*)(Bl + swz_off(nb + 0, cin)) = o[0];
  *(bf16x8*)(Bl + swz_off(nb + 1, cin)) = o[1];
  *(bf16x8*)(Bl + swz_off(nb + 2, cin)) = o[2];
  *(bf16x8*)(Bl + swz_off(nb + 3, cin)) = o[3];
}

// ---------------- phase A: fused gate+up GEMM + SwiGLU ----------------
// flat grid of 4096 blocks; bid = gg*256 + mt*8 + r, group g = gg*8+r = e*16+nt
// -> all m-blocks of one (e,nt) share bid%8, i.e. land on one XCD's L2.
template <typename WT>
__global__ __launch_bounds__(256, 2) void k_gemm_up(
    const unsigned short* __restrict__ Abf, const WT* __restrict__ wi0,
    const WT* __restrict__ wi1, const int* __restrict__ base,
    unsigned short* __restrict__ act) {
  const int bid = blockIdx.x;
  const int gg = bid >> 8, mt = (bid >> 3) & 31, r8 = bid & 7;
  const int g = gg * 8 + r8;
  const int e = g >> 4, nt = g & 15;
  const int rbase = base[e], rend = base[e + 1];
  const int ne = rend - rbase;
  if (mt * 128 >= ne) return;

  __shared__ __align__(16) unsigned short lds[32768];  // 64KB: A0|A1|Bg|Bu
  unsigned short* Bg = lds + 16384;
  unsigned short* Bu = lds + 24576;

  const int tid = threadIdx.x;
  const int wv = tid >> 6, l = tid & 63;
  const int wm = wv >> 1, wn = wv & 1;
  const WT* W0 = wi0 + (size_t)e * HDIM * DDIM + nt * 128;
  const WT* W1 = wi1 + (size_t)e * HDIM * DDIM + nt * 128;
  const int nb = (tid & 31) * 4, kb = (tid >> 5) * 8;

  f32x4 accg[4][4], accu[4][4];
#pragma unroll
  for (int i = 0; i < 4; i++)
#pragma unroll
    for (int j = 0; j < 4; j++) {
      accg[i][j] = {0.f, 0.f, 0.f, 0.f};
      accu[i][j] = {0.f, 0.f, 0.f, 0.f};
    }

  // prologue: A(0) DMA, B(0) regs -> LDS, full drain + barrier
  bf16x8 pg[4], pu[4];
#pragma unroll
  for (int q = 0; q < 4; q++) {
    const int rowt = (wv * 4 + q) * 8 + (l >> 3);
    int rr = rbase + mt * 128 + rowt;
    if (rr >= rend) rr = rend - 1;
    gload_lds16(Abf + (size_t)rr * HDIM + (((l & 7) ^ swz_q(rowt)) << 3),
                lds + (wv * 4 + q) * 512);
  }
  loadBtile(W0, DDIM, 0, nb, kb, pg);
  loadBtile(W1, DDIM, 0, nb, kb, pu);
  storeBtile(Bg, nb, kb, pg);
  storeBtile(Bu, nb, kb, pu);
  BAR_FULL();

  int cur = 0;
  for (int t = 0; t < 16; ++t) {
    // issue next tile's loads; they stay in flight under the MFMA phase
    if (t + 1 < 16) {
      const int k1 = (t + 1) * 64;
      const int noff = (cur ^ 1) * 8192;
#pragma unroll
      for (int q = 0; q < 4; q++) {
        const int rowt = (wv * 4 + q) * 8 + (l >> 3);
        int rr = rbase + mt * 128 + rowt;
        if (rr >= rend) rr = rend - 1;
        gload_lds16(Abf + (size_t)rr * HDIM + k1 +
                        (((l & 7) ^ swz_q(rowt)) << 3),
                    lds + noff + (wv * 4 + q) * 512);
      }
      loadBtile(W0, DDIM, k1, nb, kb, pg);
      loadBtile(W1, DDIM, k1, nb, kb, pu);
    }
    const unsigned short* Al = lds + cur * 8192;
    __builtin_amdgcn_s_setprio(1);
#pragma unroll
    for (int kk = 0; kk < 2; kk++) {
      bf16x8 af[4], bg[4], bu[4];
#pragma unroll
      for (int mi = 0; mi < 4; mi++) {
        const int row = wm * 64 + mi * 16 + (l & 15);
        af[mi] = *(const bf16x8*)(Al + swz_off(row, kk * 4 + (l >> 4)));
      }
#pragma unroll
      for (int ni = 0; ni < 4; ni++) {
        const int row = wn * 64 + ni * 16 + (l & 15);
        const int off = swz_off(row, kk * 4 + (l >> 4));
        bg[ni] = *(const bf16x8*)(Bg + off);
        bu[ni] = *(const bf16x8*)(Bu + off);
      }
#pragma unroll
      for (int mi = 0; mi < 4; mi++)
#pragma unroll
        for (int ni = 0; ni < 4; ni++) {
          accg[mi][ni] = __builtin_amdgcn_mfma_f32_16x16x32_bf16(
              af[mi], bg[ni], accg[mi][ni], 0, 0, 0);
          accu[mi][ni] = __builtin_amdgcn_mfma_f32_16x16x32_bf16(
              af[mi], bu[ni], accu[mi][ni], 0, 0, 0);
        }
    }
    __builtin_amdgcn_s_setprio(0);
    BAR_LGKM();  // all waves done reading Bg/Bu + A[cur]
    if (t + 1 < 16) {
      storeBtile(Bg, nb, kb, pg);
      storeBtile(Bu, nb, kb, pu);
    }
    BAR_FULL();  // A(t+1) DMA drained (hidden under MFMA) + B writes synced
    cur ^= 1;
  }
  // epilogue: silu(g)*u -> bf16 -> LDS (swizzled) -> coalesced global
  unsigned short* Cl = lds;
#pragma unroll
  for (int mi = 0; mi < 4; mi++)
#pragma unroll
    for (int ni = 0; ni < 4; ni++) {
      const int col = wn * 64 + ni * 16 + (l & 15);
#pragma unroll
      for (int rr = 0; rr < 4; rr++) {
        const int row = wm * 64 + mi * 16 + (l >> 4) * 4 + rr;
        const float gv = accg[mi][ni][rr];
        const float uv = accu[mi][ni][rr];
        const float a = (gv / (1.f + __expf(-gv))) * uv;
        Cl[cswz(row, col)] = f2b(a);
      }
    }
  __syncthreads();
  {
    const int row = tid >> 1, half = tid & 1;
    const int rw = rbase + mt * 128 + row;
    if (rw < rend) {
      unsigned short* dst = act + (size_t)rw * DDIM + nt * 128 + half * 64;
#pragma unroll
      for (int q = 0; q < 8; q++) {
        const int c = half * 8 + q;
        *(bf16x8*)(dst + q * 8) =
            *(const bf16x8*)(Cl + row * 128 + ((c ^ (row & 15)) << 3));
      }
    }
  }
}

// ---------------- phase B: down-proj GEMM ----------------
// flat grid of 2048 blocks; bid = gg*256 + mt*8 + r, g = gg*8+r = e*8+nt
template <typename WT>
__global__ __launch_bounds__(256, 2) void k_gemm_down(
    const unsigned short* __restrict__ act, const WT* __restrict__ wo,
    const int* __restrict__ base, unsigned short* __restrict__ Y) {
  const int bid = blockIdx.x;
  const int gg = bid >> 8, mt = (bid >> 3) & 31, r8 = bid & 7;
  const int g = gg * 8 + r8;
  const int e = g >> 3, nt = g & 7;
  const int rbase = base[e], rend = base[e + 1];
  const int ne = rend - rbase;
  if (mt * 128 >= ne) return;

  __shared__ __align__(16) unsigned short lds[24576];  // 48KB: A0|A1|Bw
  unsigned short* Bw = lds + 16384;

  const int tid = threadIdx.x;
  const int wv = tid >> 6, l = tid & 63;
  const int wm = wv >> 1, wn = wv & 1;
  const WT* W = wo + (size_t)e * DDIM * HDIM + nt * 128;
  const int nb = (tid & 31) * 4, kb = (tid >> 5) * 8;

  f32x4 acc[4][4];
#pragma unroll
  for (int i = 0; i < 4; i++)
#pragma unroll
    for (int j = 0; j < 4; j++) acc[i][j] = {0.f, 0.f, 0.f, 0.f};

  bf16x8 pw[4];
#pragma unroll
  for (int q = 0; q < 4; q++) {
    const int rowt = (wv * 4 + q) * 8 + (l >> 3);
    int rr = rbase + mt * 128 + rowt;
    if (rr >= rend) rr = rend - 1;
    gload_lds16(act + (size_t)rr * DDIM + (((l & 7) ^ swz_q(rowt)) << 3),
                lds + (wv * 4 + q) * 512);
  }
  loadBtile(W, HDIM, 0, nb, kb, pw);
  storeBtile(Bw, nb, kb, pw);
  BAR_FULL();

  int cur = 0;
  for (int t = 0; t < 32; ++t) {
    if (t + 1 < 32) {
      const int k1 = (t + 1) * 64;
      const int noff = (cur ^ 1) * 8192;
#pragma unroll
      for (int q = 0; q < 4; q++) {
        const int rowt = (wv * 4 + q) * 8 + (l >> 3);
        int rr = rbase + mt * 128 + rowt;
        if (rr >= rend) rr = rend - 1;
        gload_lds16(act + (size_t)rr * DDIM + k1 +
                        (((l & 7) ^ swz_q(rowt)) << 3),
                    lds + noff + (wv * 4 + q) * 512);
      }
      loadBtile(W, HDIM, k1, nb, kb, pw);
    }
    const unsigned short* Al = lds + cur * 8192;
    __builtin_amdgcn_s_setprio(1);
#pragma unroll
    for (int kk = 0; kk < 2; kk++) {
      bf16x8 af[4], bw[4];
#pragma unroll
      for (int mi = 0; mi < 4; mi++) {
        const int row = wm * 64 + mi * 16 + (l & 15);
        af[mi] = *(const bf16x8*)(Al + swz_off(row, kk * 4 + (l >> 4)));
      }
#pragma unroll
      for (int ni = 0; ni < 4; ni++) {
        const int row = wn * 64 + ni * 16 + (l & 15);
        bw[ni] = *(const bf16x8*)(Bw + swz_off(row, kk * 4 + (l >> 4)));
      }
#pragma unroll
      for (int mi = 0; mi < 4; mi++)
#pragma unroll
        for (int ni = 0; ni < 4; ni++)
          acc[mi][ni] = __builtin_amdgcn_mfma_f32_16x16x32_bf16(
              af[mi], bw[ni], acc[mi][ni], 0, 0, 0);
    }
    __builtin_amdgcn_s_setprio(0);
    BAR_LGKM();
    if (t + 1 < 32) storeBtile(Bw, nb, kb, pw);
    BAR_FULL();
    cur ^= 1;
  }
  unsigned short* Cl = lds;  // [128][128] bf16 = 32KB
#pragma unroll
  for (int mi = 0; mi < 4; mi++)
#pragma unroll
    for (int ni = 0; ni < 4; ni++) {
      const int col = wn * 64 + ni * 16 + (l & 15);
#pragma unroll
      for (int rr = 0; rr < 4; rr++) {
        const int row = wm * 64 + mi * 16 + (l >> 4) * 4 + rr;
        Cl[cswz(row, col)] = f2b(acc[mi][ni][rr]);
      }
    }
  __syncthreads();
  {
    const int row = tid >> 1, half = tid & 1;
    const int rw = rbase + mt * 128 + row;
    if (rw < rend) {
      unsigned short* dst = Y + (size_t)rw * HDIM + nt * 128 + half * 64;
#pragma unroll
      for (int q = 0; q < 8; q++) {
        const int c = half * 8 + q;
        *(bf16x8*)(dst + q * 8) =
            *(const bf16x8*)(Cl + row * 128 + ((c ^ (row & 15)) << 3));
      }
    }
  }
}

// ---------------- combine: out[t] = w0*Y[r0] + w1*Y[r1] ----------------
__global__ __launch_bounds__(256) void k_combine(
    const unsigned short* __restrict__ Y, const int* __restrict__ tokSlot,
    const float* __restrict__ tokW, float* __restrict__ out) {
  const int t = blockIdx.x;
  const int tid = threadIdx.x;
  int r0 = tokSlot[t * 2];
  const int r1 = tokSlot[t * 2 + 1];
  float w0 = tokW[t * 2];
  const float w1 = tokW[t * 2 + 1];
  if (r0 < 0) { w0 = 0.f; r0 = r1; }
  const ushort4 a = *(const ushort4*)(Y + (size_t)r0 * HDIM + tid * 4);
  const ushort4 b = *(const ushort4*)(Y + (size_t)r1 * HDIM + tid * 4);
  float4 o;
  o.x = w0 * b2f(a.x) + w1 * b2f(b.x);
  o.y = w0 * b2f(a.y) + w1 * b2f(b.y);
  o.z = w0 * b2f(a.z) + w1 * b2f(b.z);
  o.w = w0 * b2f(a.w) + w1 * b2f(b.w);
  *(float4*)(out + (size_t)t * HDIM + tid * 4) = o;
}

extern "C" void kernel_launch(void* const* d_in, const int* in_sizes, int n_in,
                              void* d_out, int out_size, void* d_ws,
                              size_t ws_size, hipStream_t stream) {
  const float* hidden = (const float*)d_in[0];
  const float* tw = (const float*)d_in[1];
  const int* ids = (const int*)d_in[2];
  const float* wi0 = (const float*)d_in[3];
  const float* wi1 = (const float*)d_in[4];
  const float* wo = (const float*)d_in[5];
  float* out = (float*)d_out;
  char* ws = (char*)d_ws;

  int* meta = (int*)(ws + OFF_META);
  int* base = (int*)(ws + OFF_BASE);
  int* assignTok = (int*)(ws + OFF_ATOK);
  int* tokSlot = (int*)(ws + OFF_SLOT);
  float* tokW = (float*)(ws + OFF_TOKW);
  unsigned short* Abf = (unsigned short*)(ws + OFF_ABF);
  unsigned short* act = (unsigned short*)(ws + OFF_ACT);
  unsigned short* Y = (unsigned short*)(ws + OFF_Y);

  k_route<<<dim3(1), dim3(256), 0, stream>>>(ids, tw, meta, base, assignTok,
                                             tokSlot, tokW);
  k_gather<<<dim3(MAXROWS), dim3(256), 0, stream>>>(hidden, meta, assignTok,
                                                    Abf);
  if (ws_size >= WS_NEED) {
    unsigned short* W0b = (unsigned short*)(ws + OFF_W0B);
    unsigned short* W1b = (unsigned short*)(ws + OFF_W1B);
    unsigned short* Wob = (unsigned short*)(ws + OFF_WOB);
    const int n4 = NEXP * HDIM * DDIM / 4;
    k_cvtw3<<<dim3(2048, 3), dim3(256), 0, stream>>>(wi0, wi1, wo, W0b, W1b,
                                                     Wob, n4);
    k_gemm_up<unsigned short><<<dim3(4096), dim3(256), 0, stream>>>(
        Abf, W0b, W1b, base, act);
    k_gemm_down<unsigned short><<<dim3(2048), dim3(256), 0, stream>>>(
        act, Wob, base, Y);
  } else {
    k_gemm_up<float><<<dim3(4096), dim3(256), 0, stream>>>(Abf, wi0, wi1, base,
                                                           act);
    k_gemm_down<float><<<dim3(2048), dim3(256), 0, stream>>>(act, wo, base, Y);
  }
  k_combine<<<dim3(NTOK), dim3(256), 0, stream>>>(Y, tokSlot, tokW, out);
}